// Round 1
// baseline (554.325 us; speedup 1.0000x reference)
//
#include <hip/hip_runtime.h>
#include <hip/hip_bf16.h>

#define M_TOTAL 16384
#define KDIM 2048
#define NDIM 2048
#define NEXP 8
#define BM 128
#define BN 128
#define BK 64
#define MAX_ROW_TILES 136

typedef __attribute__((ext_vector_type(8))) __bf16 bf16x8;
typedef __attribute__((ext_vector_type(4))) float f32x4;

__device__ inline bf16x8 cvt8(float4 a, float4 b) {
  bf16x8 r;
  r[0] = (__bf16)a.x; r[1] = (__bf16)a.y; r[2] = (__bf16)a.z; r[3] = (__bf16)a.w;
  r[4] = (__bf16)b.x; r[5] = (__bf16)b.y; r[6] = (__bf16)b.z; r[7] = (__bf16)b.w;
  return r;
}

__global__ __launch_bounds__(256) void moe_gemm_kernel(
    const float* __restrict__ x, const float* __restrict__ w,
    const int* __restrict__ ms, float* __restrict__ out) {
  __shared__ __align__(16) char As[BM * BK * 2];  // bf16 tile, swizzled
  __shared__ __align__(16) char Bs[BN * BK * 2];

  // ---- map blockIdx.y -> (expert e, row0, rows) ; uniform scalar work ----
  int sizes[NEXP];
#pragma unroll
  for (int i = 0; i < NEXP; ++i) sizes[i] = ms[i];
  const int bt = blockIdx.y;
  int e = 0, row0 = 0, rows = 0, acc_t = 0, start = 0;
  bool found = false;
#pragma unroll
  for (int i = 0; i < NEXP; ++i) {
    int nt = (sizes[i] + BM - 1) >> 7;
    if (!found && bt < acc_t + nt) {
      found = true;
      e = i;
      int t = bt - acc_t;
      row0 = start + t * BM;
      rows = sizes[i] - t * BM;
      if (rows > BM) rows = BM;
    }
    acc_t += nt;
    start += sizes[i];
  }
  if (!found) return;

  const int tid = threadIdx.x;
  const int lane = tid & 63;
  const int wave = tid >> 6;
  const int wm = wave >> 1, wn = wave & 1;   // 2x2 waves, 64x64 each
  const int col0 = blockIdx.x * BN;
  const float* wbase = w + (size_t)e * (size_t)NDIM * KDIM;

  // staging: thread -> (row sr, half sh); each thread moves 32 floats of A and B
  const int sr = tid >> 1;   // 0..127
  const int sh = tid & 1;    // cols [sh*32, sh*32+32)
  const float* aptr = x + (size_t)(row0 + sr) * KDIM + sh * 32;
  const float* bptr = wbase + (size_t)(col0 + sr) * KDIM + sh * 32;
  const bool aval = (sr < rows);

  f32x4 acc[4][4];
  const f32x4 zero = {0.f, 0.f, 0.f, 0.f};
#pragma unroll
  for (int i = 0; i < 4; ++i)
#pragma unroll
    for (int j = 0; j < 4; ++j) acc[i][j] = zero;

  for (int kb = 0; kb < KDIM / BK; ++kb) {
    // ---- stage A (x rows) ----
    {
      float4 v[8];
      if (aval) {
        const float4* p = (const float4*)(aptr + kb * BK);
#pragma unroll
        for (int j = 0; j < 8; ++j) v[j] = p[j];
      } else {
#pragma unroll
        for (int j = 0; j < 8; ++j) v[j] = make_float4(0.f, 0.f, 0.f, 0.f);
      }
#pragma unroll
      for (int j = 0; j < 4; ++j) {
        bf16x8 c = cvt8(v[2 * j], v[2 * j + 1]);
        int chunk = (sh * 4 + j) ^ (sr & 7);   // T2 XOR swizzle
        *(bf16x8*)(As + sr * 128 + chunk * 16) = c;
      }
    }
    // ---- stage B (weight rows = out-features) ----
    {
      const float4* p = (const float4*)(bptr + kb * BK);
      float4 u[8];
#pragma unroll
      for (int j = 0; j < 8; ++j) u[j] = p[j];
#pragma unroll
      for (int j = 0; j < 4; ++j) {
        bf16x8 c = cvt8(u[2 * j], u[2 * j + 1]);
        int chunk = (sh * 4 + j) ^ (sr & 7);
        *(bf16x8*)(Bs + sr * 128 + chunk * 16) = c;
      }
    }
    __syncthreads();

#pragma unroll
    for (int ks = 0; ks < 2; ++ks) {
      bf16x8 af[4], bfv[4];
#pragma unroll
      for (int mt = 0; mt < 4; ++mt) {
        int r = wm * 64 + mt * 16 + (lane & 15);
        int chunk = (ks * 4 + (lane >> 4)) ^ (r & 7);
        af[mt] = *(const bf16x8*)(As + r * 128 + chunk * 16);
      }
#pragma unroll
      for (int nt = 0; nt < 4; ++nt) {
        int r = wn * 64 + nt * 16 + (lane & 15);
        int chunk = (ks * 4 + (lane >> 4)) ^ (r & 7);
        bfv[nt] = *(const bf16x8*)(Bs + r * 128 + chunk * 16);
      }
#pragma unroll
      for (int mt = 0; mt < 4; ++mt)
#pragma unroll
        for (int nt = 0; nt < 4; ++nt)
          acc[mt][nt] = __builtin_amdgcn_mfma_f32_16x16x32_bf16(
              af[mt], bfv[nt], acc[mt][nt], 0, 0, 0);
    }
    __syncthreads();
  }

  // ---- epilogue: C/D layout col=lane&15, row=(lane>>4)*4+j ----
#pragma unroll
  for (int mt = 0; mt < 4; ++mt) {
#pragma unroll
    for (int j = 0; j < 4; ++j) {
      int r = wm * 64 + mt * 16 + (lane >> 4) * 4 + j;
      if (r < rows) {
        float* op = out + (size_t)(row0 + r) * NDIM + col0 + wn * 64 + (lane & 15);
#pragma unroll
        for (int nt = 0; nt < 4; ++nt) op[nt * 16] = acc[mt][nt][j];
      }
    }
  }
}

extern "C" void kernel_launch(void* const* d_in, const int* in_sizes, int n_in,
                              void* d_out, int out_size, void* d_ws, size_t ws_size,
                              hipStream_t stream) {
  const float* x = (const float*)d_in[0];
  const float* w = (const float*)d_in[1];
  const int* ms = (const int*)d_in[2];
  float* out = (float*)d_out;
  dim3 grid(NDIM / BN, MAX_ROW_TILES);
  moe_gemm_kernel<<<grid, dim3(256), 0, stream>>>(x, w, ms, out);
}

// Round 2
// 336.761 us; speedup vs baseline: 1.6461x; 1.6461x over previous
//
#include <hip/hip_runtime.h>
#include <hip/hip_bf16.h>

#define M_TOTAL 16384
#define KDIM 2048
#define NDIM 2048
#define NEXP 8
#define BM 128
#define BN 128
#define BK 32
#define MAX_ROW_TILES 136

typedef __attribute__((ext_vector_type(8))) __bf16 bf16x8;
typedef __attribute__((ext_vector_type(4))) float f32x4;

__device__ inline int minI(int a, int b) { return a < b ? a : b; }

__device__ inline bf16x8 cvt8(float4 a, float4 b) {
  bf16x8 r;
  r[0] = (__bf16)a.x; r[1] = (__bf16)a.y; r[2] = (__bf16)a.z; r[3] = (__bf16)a.w;
  r[4] = (__bf16)b.x; r[5] = (__bf16)b.y; r[6] = (__bf16)b.z; r[7] = (__bf16)b.w;
  return r;
}

__device__ inline void gload16(const void* g, void* l) {
  __builtin_amdgcn_global_load_lds(
      (const __attribute__((address_space(1))) void*)g,
      (__attribute__((address_space(3))) void*)l, 16, 0, 0);
}

// ---------------- fp32 -> bf16 conversion (x then W) ----------------
__global__ __launch_bounds__(256) void cvt_both(
    const float* __restrict__ x, const float* __restrict__ w,
    bf16x8* __restrict__ xb, bf16x8* __restrict__ wb) {
  const int NX = (M_TOTAL * KDIM) / 8;
  const int NW = (NEXP * NDIM * KDIM) / 8;
  const int stride = gridDim.x * blockDim.x;
  for (int i = blockIdx.x * blockDim.x + threadIdx.x; i < NX + NW; i += stride) {
    const float4* src = (i < NX) ? ((const float4*)x + (size_t)i * 2)
                                 : ((const float4*)w + (size_t)(i - NX) * 2);
    float4 a = src[0], b = src[1];
    bf16x8 c = cvt8(a, b);
    if (i < NX) xb[i] = c; else wb[i - NX] = c;
  }
}

// ---------------- main grouped GEMM, m97 structure ----------------
__global__ __launch_bounds__(256) void moe_gemm_bf16(
    const __hip_bfloat16* __restrict__ xb, const __hip_bfloat16* __restrict__ wb,
    const int* __restrict__ ms, float* __restrict__ out) {
  __shared__ __align__(16) __hip_bfloat16 As[BM * BK];  // [128][32] linear
  __shared__ __align__(16) __hip_bfloat16 Bs[BN * BK];

  // ---- map blockIdx.y -> (expert e, row0, rows) ----
  int sizes[NEXP];
#pragma unroll
  for (int i = 0; i < NEXP; ++i) sizes[i] = ms[i];
  const int bt = blockIdx.y;
  int e = 0, row0 = 0, rows = 0, acc_t = 0, start = 0;
  bool found = false;
#pragma unroll
  for (int i = 0; i < NEXP; ++i) {
    int nt = (sizes[i] + BM - 1) >> 7;
    if (!found && bt < acc_t + nt) {
      found = true;
      e = i;
      int t = bt - acc_t;
      row0 = start + t * BM;
      rows = sizes[i] - t * BM;
      if (rows > BM) rows = BM;
    }
    acc_t += nt;
    start += sizes[i];
  }
  if (!found) return;

  const int tid = threadIdx.x;
  const int lane = tid & 63;
  const int wave = tid >> 6;
  const int wm = wave >> 1, wn = wave & 1;  // 2x2 waves, 64x64 each
  const int col0 = blockIdx.x * BN;

  // ---- staging: wave w covers LDS bytes [w*2048, w*2048+2048) in 2 issues ----
  // byte off = w*2048 + i*1024 + lane*16 -> row = off>>6, k-quarter = (off>>4)&3
  const int rS = wave * 32 + (lane >> 2);
  const int q8 = (lane & 3) * 8;
  const __hip_bfloat16* aSrc0 = xb + (size_t)minI(row0 + rS, M_TOTAL - 1) * KDIM + q8;
  const __hip_bfloat16* aSrc1 = xb + (size_t)minI(row0 + rS + 16, M_TOTAL - 1) * KDIM + q8;
  const __hip_bfloat16* wbase = wb + (size_t)e * NDIM * KDIM;
  const __hip_bfloat16* bSrc0 = wbase + (size_t)(col0 + rS) * KDIM + q8;
  const __hip_bfloat16* bSrc1 = wbase + (size_t)(col0 + rS + 16) * KDIM + q8;
  char* AsB0 = (char*)As + wave * 2048;  // wave-uniform LDS bases
  char* AsB1 = AsB0 + 1024;
  char* BsB0 = (char*)Bs + wave * 2048;
  char* BsB1 = BsB0 + 1024;

  f32x4 acc[4][4];
  const f32x4 zero = {0.f, 0.f, 0.f, 0.f};
#pragma unroll
  for (int i = 0; i < 4; ++i)
#pragma unroll
    for (int j = 0; j < 4; ++j) acc[i][j] = zero;

  const int fr = lane & 15;
  const int fcb = (lane >> 4) * 16;  // byte offset of k-quarter

  for (int kb = 0; kb < KDIM / BK; ++kb) {
    const int ko = kb * BK;
    gload16(aSrc0 + ko, AsB0);
    gload16(aSrc1 + ko, AsB1);
    gload16(bSrc0 + ko, BsB0);
    gload16(bSrc1 + ko, BsB1);
    __syncthreads();  // vmcnt(0): tiles landed

    bf16x8 af[4], bv[4];
#pragma unroll
    for (int mt = 0; mt < 4; ++mt)
      af[mt] = *(const bf16x8*)((const char*)As + (wm * 64 + mt * 16 + fr) * 64 + fcb);
#pragma unroll
    for (int nt = 0; nt < 4; ++nt)
      bv[nt] = *(const bf16x8*)((const char*)Bs + (wn * 64 + nt * 16 + fr) * 64 + fcb);
#pragma unroll
    for (int mt = 0; mt < 4; ++mt)
#pragma unroll
      for (int nt = 0; nt < 4; ++nt)
        acc[mt][nt] = __builtin_amdgcn_mfma_f32_16x16x32_bf16(
            af[mt], bv[nt], acc[mt][nt], 0, 0, 0);
    __syncthreads();  // LDS free for next stage
  }

  // ---- epilogue: C/D layout col=lane&15, row=(lane>>4)*4+j ----
#pragma unroll
  for (int mt = 0; mt < 4; ++mt) {
#pragma unroll
    for (int j = 0; j < 4; ++j) {
      int r = wm * 64 + mt * 16 + (lane >> 4) * 4 + j;
      if (r < rows) {
        float* op = out + (size_t)(row0 + r) * NDIM + col0 + wn * 64 + (lane & 15);
#pragma unroll
        for (int nt = 0; nt < 4; ++nt) op[nt * 16] = acc[mt][nt][j];
      }
    }
  }
}

// ---------------- fallback (round-1 kernel): direct fp32, reg-staged ----------------
__global__ __launch_bounds__(256) void moe_gemm_f32(
    const float* __restrict__ x, const float* __restrict__ w,
    const int* __restrict__ ms, float* __restrict__ out) {
  __shared__ __align__(16) char As[BM * 64 * 2];
  __shared__ __align__(16) char Bs[BN * 64 * 2];
  int sizes[NEXP];
#pragma unroll
  for (int i = 0; i < NEXP; ++i) sizes[i] = ms[i];
  const int bt = blockIdx.y;
  int e = 0, row0 = 0, rows = 0, acc_t = 0, start = 0;
  bool found = false;
#pragma unroll
  for (int i = 0; i < NEXP; ++i) {
    int nt = (sizes[i] + BM - 1) >> 7;
    if (!found && bt < acc_t + nt) {
      found = true;
      e = i;
      int t = bt - acc_t;
      row0 = start + t * BM;
      rows = sizes[i] - t * BM;
      if (rows > BM) rows = BM;
    }
    acc_t += nt;
    start += sizes[i];
  }
  if (!found) return;
  const int tid = threadIdx.x;
  const int lane = tid & 63;
  const int wave = tid >> 6;
  const int wm = wave >> 1, wn = wave & 1;
  const int col0 = blockIdx.x * BN;
  const float* wbase = w + (size_t)e * (size_t)NDIM * KDIM;
  const int sr = tid >> 1;
  const int sh = tid & 1;
  const float* aptr = x + (size_t)(row0 + sr) * KDIM + sh * 32;
  const float* bptr = wbase + (size_t)(col0 + sr) * KDIM + sh * 32;
  const bool aval = (sr < rows);
  f32x4 acc[4][4];
  const f32x4 zero = {0.f, 0.f, 0.f, 0.f};
#pragma unroll
  for (int i = 0; i < 4; ++i)
#pragma unroll
    for (int j = 0; j < 4; ++j) acc[i][j] = zero;
  for (int kb = 0; kb < KDIM / 64; ++kb) {
    {
      float4 v[8];
      if (aval) {
        const float4* p = (const float4*)(aptr + kb * 64);
#pragma unroll
        for (int j = 0; j < 8; ++j) v[j] = p[j];
      } else {
#pragma unroll
        for (int j = 0; j < 8; ++j) v[j] = make_float4(0.f, 0.f, 0.f, 0.f);
      }
#pragma unroll
      for (int j = 0; j < 4; ++j) {
        bf16x8 c = cvt8(v[2 * j], v[2 * j + 1]);
        int chunk = (sh * 4 + j) ^ (sr & 7);
        *(bf16x8*)(As + sr * 128 + chunk * 16) = c;
      }
    }
    {
      const float4* p = (const float4*)(bptr + kb * 64);
      float4 u[8];
#pragma unroll
      for (int j = 0; j < 8; ++j) u[j] = p[j];
#pragma unroll
      for (int j = 0; j < 4; ++j) {
        bf16x8 c = cvt8(u[2 * j], u[2 * j + 1]);
        int chunk = (sh * 4 + j) ^ (sr & 7);
        *(bf16x8*)(Bs + sr * 128 + chunk * 16) = c;
      }
    }
    __syncthreads();
#pragma unroll
    for (int ks = 0; ks < 2; ++ks) {
      bf16x8 af[4], bfv[4];
#pragma unroll
      for (int mt = 0; mt < 4; ++mt) {
        int r = wm * 64 + mt * 16 + (lane & 15);
        int chunk = (ks * 4 + (lane >> 4)) ^ (r & 7);
        af[mt] = *(const bf16x8*)(As + r * 128 + chunk * 16);
      }
#pragma unroll
      for (int nt = 0; nt < 4; ++nt) {
        int r = wn * 64 + nt * 16 + (lane & 15);
        int chunk = (ks * 4 + (lane >> 4)) ^ (r & 7);
        bfv[nt] = *(const bf16x8*)(Bs + r * 128 + chunk * 16);
      }
#pragma unroll
      for (int mt = 0; mt < 4; ++mt)
#pragma unroll
        for (int nt = 0; nt < 4; ++nt)
          acc[mt][nt] = __builtin_amdgcn_mfma_f32_16x16x32_bf16(
              af[mt], bfv[nt], acc[mt][nt], 0, 0, 0);
    }
    __syncthreads();
  }
#pragma unroll
  for (int mt = 0; mt < 4; ++mt) {
#pragma unroll
    for (int j = 0; j < 4; ++j) {
      int r = wm * 64 + mt * 16 + (lane >> 4) * 4 + j;
      if (r < rows) {
        float* op = out + (size_t)(row0 + r) * NDIM + col0 + wn * 64 + (lane & 15);
#pragma unroll
        for (int nt = 0; nt < 4; ++nt) op[nt * 16] = acc[mt][nt][j];
      }
    }
  }
}

extern "C" void kernel_launch(void* const* d_in, const int* in_sizes, int n_in,
                              void* d_out, int out_size, void* d_ws, size_t ws_size,
                              hipStream_t stream) {
  const float* x = (const float*)d_in[0];
  const float* w = (const float*)d_in[1];
  const int* ms = (const int*)d_in[2];
  float* out = (float*)d_out;
  const size_t nx = (size_t)M_TOTAL * KDIM;
  const size_t nw = (size_t)NEXP * NDIM * KDIM;
  const size_t need = (nx + nw) * sizeof(__hip_bfloat16);
  dim3 grid(NDIM / BN, MAX_ROW_TILES);
  if (ws_size >= need) {
    __hip_bfloat16* xb = (__hip_bfloat16*)d_ws;
    __hip_bfloat16* wb = xb + nx;
    cvt_both<<<2048, 256, 0, stream>>>(x, w, (bf16x8*)xb, (bf16x8*)wb);
    moe_gemm_bf16<<<grid, dim3(256), 0, stream>>>(xb, wb, ms, out);
  } else {
    moe_gemm_f32<<<grid, dim3(256), 0, stream>>>(x, w, ms, out);
  }
}

// Round 3
// 260.813 us; speedup vs baseline: 2.1254x; 1.2912x over previous
//
#include <hip/hip_runtime.h>
#include <hip/hip_bf16.h>

#define M_TOTAL 16384
#define KDIM 2048
#define NDIM 2048
#define NEXP 8
#define BM 256
#define BN 256
#define BK 32
#define NKT 64            // KDIM / BK
#define MAX_ROW_TILES 71  // 16384/256 + 7 possible boundary extras
#define NWG (MAX_ROW_TILES * 8)

typedef __attribute__((ext_vector_type(8))) __bf16 bf16x8;
typedef __attribute__((ext_vector_type(4))) float f32x4;

__device__ inline int minI(int a, int b) { return a < b ? a : b; }

__device__ inline bf16x8 cvt8(float4 a, float4 b) {
  bf16x8 r;
  r[0] = (__bf16)a.x; r[1] = (__bf16)a.y; r[2] = (__bf16)a.z; r[3] = (__bf16)a.w;
  r[4] = (__bf16)b.x; r[5] = (__bf16)b.y; r[6] = (__bf16)b.z; r[7] = (__bf16)b.w;
  return r;
}

__device__ inline void gload16(const void* g, void* l) {
  __builtin_amdgcn_global_load_lds(
      (const __attribute__((address_space(1))) void*)g,
      (__attribute__((address_space(3))) void*)l, 16, 0, 0);
}

__device__ inline void fencedBarrier() {
  asm volatile("" ::: "memory");
  __builtin_amdgcn_s_barrier();
  asm volatile("" ::: "memory");
}

// ---------------- fp32 -> bf16 conversion (x then W) ----------------
__global__ __launch_bounds__(256) void cvt_both(
    const float* __restrict__ x, const float* __restrict__ w,
    bf16x8* __restrict__ xb, bf16x8* __restrict__ wb) {
  const int NX = (M_TOTAL * KDIM) / 8;
  const int NW = (NEXP * NDIM * KDIM) / 8;
  const int stride = gridDim.x * blockDim.x;
  for (int i = blockIdx.x * blockDim.x + threadIdx.x; i < NX + NW; i += stride) {
    const float4* src = (i < NX) ? ((const float4*)x + (size_t)i * 2)
                                 : ((const float4*)w + (size_t)(i - NX) * 2);
    float4 a = src[0], b = src[1];
    bf16x8 c = cvt8(a, b);
    if (i < NX) xb[i] = c; else wb[i - NX] = c;
  }
}

// ---------------- grouped GEMM: 256x256 tile, BK=32, 4-buffer deep pipeline ----------------
// LDS layout: buf b (0..3) at b*32768; A tile [256 rows][32 cols bf16] as two
// 128-row halves of 8KB at +0/+8192; B tile (weight rows) at +16384 likewise.
// Within a half: physical byte = row*64 + p*16, logical chunk c stored at
// p = c ^ ((row>>1)&3)  (bank-spread swizzle; fragment reads <=2-way = free).
// global_load_lds writes linearly (wave-uniform base + lane*16), so the swizzle
// is applied by pre-swizzling the per-lane GLOBAL source column (m173 pattern).
__global__ __launch_bounds__(512, 2) void moe_gemm_8ph(
    const __hip_bfloat16* __restrict__ xb, const __hip_bfloat16* __restrict__ wb,
    const int* __restrict__ ms, float* __restrict__ out) {
  __shared__ __align__(16) char lds[131072];

  // bijective XCD swizzle (NWG = 568 = 8*71, divisible by 8)
  const int orig = blockIdx.x;
  const int wg = (orig & 7) * MAX_ROW_TILES + (orig >> 3);
  const int bt = wg >> 3;    // row-tile 0..70
  const int ntile = wg & 7;  // col-tile 0..7

  // ---- map bt -> (expert e, row0, rows) ----
  int sizes[NEXP];
#pragma unroll
  for (int i = 0; i < NEXP; ++i) sizes[i] = ms[i];
  int e = 0, row0 = 0, rows = 0, acc_t = 0, start = 0;
  bool found = false;
#pragma unroll
  for (int i = 0; i < NEXP; ++i) {
    int nt = (sizes[i] + BM - 1) >> 8;
    if (!found && bt < acc_t + nt) {
      found = true; e = i;
      int tt = bt - acc_t;
      row0 = start + tt * BM;
      rows = minI(sizes[i] - tt * BM, BM);
    }
    acc_t += nt; start += sizes[i];
  }
  if (!found) return;

  const int tid = threadIdx.x;
  const int lane = tid & 63;
  const int wave = tid >> 6;
  const int wr = wave >> 2, wc = wave & 3;  // 2x4 waves, 128x64 out each
  const int col0 = ntile * BN;

  // ---- staging addresses (pre-swizzled global source) ----
  // lane writes LDS (row = wave*16 + lane>>2, p = lane&3) within a half;
  // logical col chunk = p ^ ((row>>1)&3) = (lane&3) ^ ((lane>>3)&3)
  const int rwh = wave * 16 + (lane >> 2);
  const int colel = (((lane & 3) ^ ((lane >> 3) & 3)) << 3);
  const __hip_bfloat16* aS0 = xb + (size_t)minI(row0 + rwh, M_TOTAL - 1) * KDIM + colel;
  const __hip_bfloat16* aS1 = xb + (size_t)minI(row0 + 128 + rwh, M_TOTAL - 1) * KDIM + colel;
  const __hip_bfloat16* wbase = wb + (size_t)e * NDIM * KDIM;
  const __hip_bfloat16* bS0 = wbase + (size_t)(col0 + rwh) * KDIM + colel;
  const __hip_bfloat16* bS1 = wbase + (size_t)(col0 + 128 + rwh) * KDIM + colel;
  char* stBase = lds + wave * 1024;

  // ---- fragment read bases (swizzled) ----
  const int fr = lane & 15, fc = lane >> 4;
  const int laneOff = fr * 64 + ((fc ^ ((fr >> 1) & 3)) << 4);
  const char* pA0 = lds + wr * 8192 + laneOff;
  const char* pB0 = lds + 16384 + (wc >> 1) * 8192 + (wc & 1) * 4096 + laneOff;

  f32x4 acc[8][4];
  const f32x4 zero = {0.f, 0.f, 0.f, 0.f};
#pragma unroll
  for (int i = 0; i < 8; ++i)
#pragma unroll
    for (int j = 0; j < 4; ++j) acc[i][j] = zero;

#define ISSUE_A(T) { char* b_ = stBase + ((T) & 3) * 32768; \
    gload16(aS0 + (size_t)(T) * BK, b_); gload16(aS1 + (size_t)(T) * BK, b_ + 8192); }
#define ISSUE_B(T) { char* b_ = stBase + ((T) & 3) * 32768 + 16384; \
    gload16(bS0 + (size_t)(T) * BK, b_); gload16(bS1 + (size_t)(T) * BK, b_ + 8192); }

  // prologue: tiles 0,1,2 in flight (12 loads/thread); wait tile 0 (oldest 4)
  ISSUE_A(0) ISSUE_B(0) ISSUE_A(1) ISSUE_B(1) ISSUE_A(2) ISSUE_B(2)
  asm volatile("s_waitcnt vmcnt(8)" ::: "memory");
  fencedBarrier();

  bf16x8 af[8], bv[4];
  for (int t = 0; t < NKT; ++t) {
    const char* pA = pA0 + (t & 3) * 32768;
    const char* pB = pB0 + (t & 3) * 32768;
    // ---- phase 0: ds m0-3 + n0-3, stage A(t+3), mfma m0-3 x n0-3 ----
#pragma unroll
    for (int mt = 0; mt < 4; ++mt) af[mt] = *(const bf16x8*)(pA + mt * 1024);
#pragma unroll
    for (int nt = 0; nt < 4; ++nt) bv[nt] = *(const bf16x8*)(pB + nt * 1024);
    if (t < NKT - 3) ISSUE_A(t + 3)
    __builtin_amdgcn_s_barrier();
    asm volatile("s_waitcnt lgkmcnt(0)");
    __builtin_amdgcn_s_setprio(1);
#pragma unroll
    for (int mt = 0; mt < 4; ++mt)
#pragma unroll
      for (int nt = 0; nt < 4; ++nt)
        acc[mt][nt] = __builtin_amdgcn_mfma_f32_16x16x32_bf16(
            af[mt], bv[nt], acc[mt][nt], 0, 0, 0);
    __builtin_amdgcn_s_setprio(0);
    __builtin_amdgcn_s_barrier();
    // ---- phase 1: ds m4-7, stage B(t+3), mfma m4-7 x n0-3 ----
#pragma unroll
    for (int mt = 4; mt < 8; ++mt) af[mt] = *(const bf16x8*)(pA + mt * 1024);
    if (t < NKT - 3) ISSUE_B(t + 3)
    __builtin_amdgcn_s_barrier();
    asm volatile("s_waitcnt lgkmcnt(0)");
    __builtin_amdgcn_s_setprio(1);
#pragma unroll
    for (int mt = 4; mt < 8; ++mt)
#pragma unroll
      for (int nt = 0; nt < 4; ++nt)
        acc[mt][nt] = __builtin_amdgcn_mfma_f32_16x16x32_bf16(
            af[mt], bv[nt], acc[mt][nt], 0, 0, 0);
    __builtin_amdgcn_s_setprio(0);
    // tile boundary: counted drain — tile t+1 guaranteed landed, 2 tiles stay in flight
    if (t < NKT - 3)       { asm volatile("s_waitcnt vmcnt(8)" ::: "memory"); }
    else if (t == NKT - 3) { asm volatile("s_waitcnt vmcnt(4)" ::: "memory"); }
    else if (t == NKT - 2) { asm volatile("s_waitcnt vmcnt(0)" ::: "memory"); }
    fencedBarrier();
  }
#undef ISSUE_A
#undef ISSUE_B

  // ---- epilogue: C/D layout col=lane&15, row=(lane>>4)*4+j ----
  const int er = (lane >> 4) * 4;
#pragma unroll
  for (int mt = 0; mt < 8; ++mt) {
#pragma unroll
    for (int j = 0; j < 4; ++j) {
      int r = wr * 128 + mt * 16 + er + j;
      if (r < rows) {
        float* op = out + (size_t)(row0 + r) * NDIM + col0 + wc * 64 + (lane & 15);
#pragma unroll
        for (int nt = 0; nt < 4; ++nt) op[nt * 16] = acc[mt][nt][j];
      }
    }
  }
}

// ---------------- fallback: direct fp32, reg-staged (round-1 kernel) ----------------
__global__ __launch_bounds__(256) void moe_gemm_f32(
    const float* __restrict__ x, const float* __restrict__ w,
    const int* __restrict__ ms, float* __restrict__ out) {
  __shared__ __align__(16) char As[128 * 64 * 2];
  __shared__ __align__(16) char Bs[128 * 64 * 2];
  int sizes[NEXP];
#pragma unroll
  for (int i = 0; i < NEXP; ++i) sizes[i] = ms[i];
  const int bt = blockIdx.y;
  int e = 0, row0 = 0, rows = 0, acc_t = 0, start = 0;
  bool found = false;
#pragma unroll
  for (int i = 0; i < NEXP; ++i) {
    int nt = (sizes[i] + 127) >> 7;
    if (!found && bt < acc_t + nt) {
      found = true; e = i;
      int tt = bt - acc_t;
      row0 = start + tt * 128;
      rows = minI(sizes[i] - tt * 128, 128);
    }
    acc_t += nt; start += sizes[i];
  }
  if (!found) return;
  const int tid = threadIdx.x;
  const int lane = tid & 63;
  const int wave = tid >> 6;
  const int wm = wave >> 1, wn = wave & 1;
  const int col0 = blockIdx.x * 128;
  const float* wbase = w + (size_t)e * (size_t)NDIM * KDIM;
  const int sr = tid >> 1;
  const int sh = tid & 1;
  const float* aptr = x + (size_t)(row0 + sr) * KDIM + sh * 32;
  const float* bptr = wbase + (size_t)(col0 + sr) * KDIM + sh * 32;
  const bool aval = (sr < rows);
  f32x4 acc[4][4];
  const f32x4 zero = {0.f, 0.f, 0.f, 0.f};
#pragma unroll
  for (int i = 0; i < 4; ++i)
#pragma unroll
    for (int j = 0; j < 4; ++j) acc[i][j] = zero;
  for (int kb = 0; kb < KDIM / 64; ++kb) {
    {
      float4 v[8];
      if (aval) {
        const float4* p = (const float4*)(aptr + kb * 64);
#pragma unroll
        for (int j = 0; j < 8; ++j) v[j] = p[j];
      } else {
#pragma unroll
        for (int j = 0; j < 8; ++j) v[j] = make_float4(0.f, 0.f, 0.f, 0.f);
      }
#pragma unroll
      for (int j = 0; j < 4; ++j) {
        bf16x8 c = cvt8(v[2 * j], v[2 * j + 1]);
        int chunk = (sh * 4 + j) ^ (sr & 7);
        *(bf16x8*)(As + sr * 128 + chunk * 16) = c;
      }
    }
    {
      const float4* p = (const float4*)(bptr + kb * 64);
      float4 u[8];
#pragma unroll
      for (int j = 0; j < 8; ++j) u[j] = p[j];
#pragma unroll
      for (int j = 0; j < 4; ++j) {
        bf16x8 c = cvt8(u[2 * j], u[2 * j + 1]);
        int chunk = (sh * 4 + j) ^ (sr & 7);
        *(bf16x8*)(Bs + sr * 128 + chunk * 16) = c;
      }
    }
    __syncthreads();
#pragma unroll
    for (int ks = 0; ks < 2; ++ks) {
      bf16x8 afr[4], bfv[4];
#pragma unroll
      for (int mt = 0; mt < 4; ++mt) {
        int r = wm * 64 + mt * 16 + (lane & 15);
        int chunk = (ks * 4 + (lane >> 4)) ^ (r & 7);
        afr[mt] = *(const bf16x8*)(As + r * 128 + chunk * 16);
      }
#pragma unroll
      for (int nt = 0; nt < 4; ++nt) {
        int r = wn * 64 + nt * 16 + (lane & 15);
        int chunk = (ks * 4 + (lane >> 4)) ^ (r & 7);
        bfv[nt] = *(const bf16x8*)(Bs + r * 128 + chunk * 16);
      }
#pragma unroll
      for (int mt = 0; mt < 4; ++mt)
#pragma unroll
        for (int nt = 0; nt < 4; ++nt)
          acc[mt][nt] = __builtin_amdgcn_mfma_f32_16x16x32_bf16(
              afr[mt], bfv[nt], acc[mt][nt], 0, 0, 0);
    }
    __syncthreads();
  }
#pragma unroll
  for (int mt = 0; mt < 4; ++mt) {
#pragma unroll
    for (int j = 0; j < 4; ++j) {
      int r = wm * 64 + mt * 16 + (lane >> 4) * 4 + j;
      if (r < rows) {
        float* op = out + (size_t)(row0 + r) * NDIM + col0 + wn * 64 + (lane & 15);
#pragma unroll
        for (int nt = 0; nt < 4; ++nt) op[nt * 16] = acc[mt][nt][j];
      }
    }
  }
}

extern "C" void kernel_launch(void* const* d_in, const int* in_sizes, int n_in,
                              void* d_out, int out_size, void* d_ws, size_t ws_size,
                              hipStream_t stream) {
  const float* x = (const float*)d_in[0];
  const float* w = (const float*)d_in[1];
  const int* ms = (const int*)d_in[2];
  float* out = (float*)d_out;
  const size_t nx = (size_t)M_TOTAL * KDIM;
  const size_t nw = (size_t)NEXP * NDIM * KDIM;
  const size_t need = (nx + nw) * sizeof(__hip_bfloat16);
  if (ws_size >= need) {
    __hip_bfloat16* xb = (__hip_bfloat16*)d_ws;
    __hip_bfloat16* wb = xb + nx;
    cvt_both<<<2048, 256, 0, stream>>>(x, w, (bf16x8*)xb, (bf16x8*)wb);
    moe_gemm_8ph<<<dim3(NWG), dim3(512), 0, stream>>>(xb, wb, ms, out);
  } else {
    moe_gemm_f32<<<dim3(16, 135), dim3(256), 0, stream>>>(x, w, ms, out);
  }
}

// Round 4
// 243.479 us; speedup vs baseline: 2.2767x; 1.0712x over previous
//
#include <hip/hip_runtime.h>
#include <hip/hip_bf16.h>

#define M_TOTAL 16384
#define KDIM 2048
#define NDIM 2048
#define NEXP 8
#define BM 256
#define BN 256
#define BK 32
#define NKT 64            // KDIM / BK
#define MAX_ROW_TILES 71  // 16384/256 + 7 possible boundary extras
#define NWG (MAX_ROW_TILES * 8)

typedef __attribute__((ext_vector_type(8))) __bf16 bf16x8;
typedef __attribute__((ext_vector_type(4))) float f32x4;

__device__ inline int minI(int a, int b) { return a < b ? a : b; }

__device__ inline bf16x8 cvt8(float4 a, float4 b) {
  bf16x8 r;
  r[0] = (__bf16)a.x; r[1] = (__bf16)a.y; r[2] = (__bf16)a.z; r[3] = (__bf16)a.w;
  r[4] = (__bf16)b.x; r[5] = (__bf16)b.y; r[6] = (__bf16)b.z; r[7] = (__bf16)b.w;
  return r;
}

__device__ inline void gload16(const void* g, void* l) {
  __builtin_amdgcn_global_load_lds(
      (const __attribute__((address_space(1))) void*)g,
      (__attribute__((address_space(3))) void*)l, 16, 0, 0);
}

// ---------------- fp32 -> bf16 conversion (x then W) ----------------
__global__ __launch_bounds__(256) void cvt_both(
    const float* __restrict__ x, const float* __restrict__ w,
    bf16x8* __restrict__ xb, bf16x8* __restrict__ wb) {
  const int NX = (M_TOTAL * KDIM) / 8;
  const int NW = (NEXP * NDIM * KDIM) / 8;
  const int stride = gridDim.x * blockDim.x;
  for (int i = blockIdx.x * blockDim.x + threadIdx.x; i < NX + NW; i += stride) {
    const float4* src = (i < NX) ? ((const float4*)x + (size_t)i * 2)
                                 : ((const float4*)w + (size_t)(i - NX) * 2);
    float4 a = src[0], b = src[1];
    bf16x8 c = cvt8(a, b);
    if (i < NX) xb[i] = c; else wb[i - NX] = c;
  }
}

// ---------------- grouped GEMM: 256x256, BK=32, 4-buffer LDS + register-level
// fragment pipeline: frags for phase p issued during phase p-1 (static slots),
// 1 barrier + 1 counted vmcnt per K-tile. ----------------
__global__ __launch_bounds__(512, 2) void moe_gemm_pipe(
    const __hip_bfloat16* __restrict__ xb, const __hip_bfloat16* __restrict__ wb,
    const int* __restrict__ ms, float* __restrict__ out) {
  __shared__ __align__(16) char lds[131072];

  // bijective XCD swizzle (NWG = 568 = 8*71)
  const int orig = blockIdx.x;
  const int wg = (orig & 7) * MAX_ROW_TILES + (orig >> 3);
  const int bt = wg >> 3;
  const int ntile = wg & 7;

  int sizes[NEXP];
#pragma unroll
  for (int i = 0; i < NEXP; ++i) sizes[i] = ms[i];
  int e = 0, row0 = 0, rows = 0, acc_t = 0, start = 0;
  bool found = false;
#pragma unroll
  for (int i = 0; i < NEXP; ++i) {
    int nt = (sizes[i] + BM - 1) >> 8;
    if (!found && bt < acc_t + nt) {
      found = true; e = i;
      int tt = bt - acc_t;
      row0 = start + tt * BM;
      rows = minI(sizes[i] - tt * BM, BM);
    }
    acc_t += nt; start += sizes[i];
  }
  if (!found) return;

  const int tid = threadIdx.x;
  const int lane = tid & 63;
  const int wave = tid >> 6;
  const int wr = wave >> 2, wc = wave & 3;  // 2x4 waves, 128x64 out each
  const int col0 = ntile * BN;

  // staging (pre-swizzled global source; LDS dest linear per gload_lds rules)
  const int rwh = wave * 16 + (lane >> 2);
  const int colel = (((lane & 3) ^ ((lane >> 3) & 3)) << 3);
  const __hip_bfloat16* aS0 = xb + (size_t)minI(row0 + rwh, M_TOTAL - 1) * KDIM + colel;
  const __hip_bfloat16* aS1 = xb + (size_t)minI(row0 + 128 + rwh, M_TOTAL - 1) * KDIM + colel;
  const __hip_bfloat16* wbase = wb + (size_t)e * NDIM * KDIM;
  const __hip_bfloat16* bS0 = wbase + (size_t)(col0 + rwh) * KDIM + colel;
  const __hip_bfloat16* bS1 = wbase + (size_t)(col0 + 128 + rwh) * KDIM + colel;
  char* stBase = lds + wave * 1024;

  // fragment read offsets (swizzled, conflict-measured-0 in round 3)
  const int fr = lane & 15, fc = lane >> 4;
  const int laneOff = fr * 64 + ((fc ^ ((fr >> 1) & 3)) << 4);
  const int aOff = wr * 8192 + laneOff;        // af rows start
  const int bOff = 16384 + wc * 4096 + laneOff;

  f32x4 acc[8][4];
  const f32x4 zero = {0.f, 0.f, 0.f, 0.f};
#pragma unroll
  for (int i = 0; i < 8; ++i)
#pragma unroll
    for (int j = 0; j < 4; ++j) acc[i][j] = zero;

  bf16x8 afL0[4], afL1[4], bv0[4], bv1[4], afH[4];

#define ISSUE_A(T) { char* b_ = stBase + ((T) & 3) * 32768; \
    gload16(aS0 + (size_t)(T) * BK, b_); gload16(aS1 + (size_t)(T) * BK, b_ + 8192); }
#define ISSUE_B(T) { char* b_ = stBase + ((T) & 3) * 32768 + 16384; \
    gload16(bS0 + (size_t)(T) * BK, b_); gload16(bS1 + (size_t)(T) * BK, b_ + 8192); }
#define DS_AFH(T) { const char* bA_ = lds + ((T) & 3) * 32768 + aOff + 4096; \
    _Pragma("unroll") for (int mt = 0; mt < 4; ++mt) \
      afH[mt] = *(const bf16x8*)(bA_ + mt * 1024); }
#define DS_NEXT(T, S) { const char* bb_ = lds + ((T) & 3) * 32768; \
    _Pragma("unroll") for (int mt = 0; mt < 4; ++mt) \
      afL##S[mt] = *(const bf16x8*)(bb_ + aOff + mt * 1024); \
    _Pragma("unroll") for (int nt = 0; nt < 4; ++nt) \
      bv##S[nt] = *(const bf16x8*)(bb_ + bOff + nt * 1024); }
#define MFMA_P0(S) { _Pragma("unroll") for (int mt = 0; mt < 4; ++mt) \
    _Pragma("unroll") for (int nt = 0; nt < 4; ++nt) \
      acc[mt][nt] = __builtin_amdgcn_mfma_f32_16x16x32_bf16( \
          afL##S[mt], bv##S[nt], acc[mt][nt], 0, 0, 0); }
#define MFMA_P1(S) { _Pragma("unroll") for (int mt = 0; mt < 4; ++mt) \
    _Pragma("unroll") for (int nt = 0; nt < 4; ++nt) \
      acc[mt + 4][nt] = __builtin_amdgcn_mfma_f32_16x16x32_bf16( \
          afH[mt], bv##S[nt], acc[mt + 4][nt], 0, 0, 0); }

// One K-tile: phase0 {afH-issue, stage A(T+3), MFMA m0-3} ;
// phase1 {vmcnt, barrier, next-tile frag issue, stage B(T+3), MFMA m4-7}
#define TILE(T, S, SN, IA, IB, VMNSTR, NF) { \
    DS_AFH(T); \
    if (IA) ISSUE_A((T) + 3); \
    __builtin_amdgcn_s_setprio(1); MFMA_P0(S); __builtin_amdgcn_s_setprio(0); \
    asm volatile("s_waitcnt " VMNSTR ::: "memory"); \
    __builtin_amdgcn_s_barrier(); \
    if (NF) DS_NEXT((T) + 1, SN); \
    if (IB) ISSUE_B((T) + 3); \
    __builtin_amdgcn_s_setprio(1); MFMA_P1(S); __builtin_amdgcn_s_setprio(0); }

  // prologue: tiles 0,1,2 in flight; wait tile 0 (leave 8); preload frags
  ISSUE_A(0) ISSUE_B(0) ISSUE_A(1) ISSUE_B(1) ISSUE_A(2) ISSUE_B(2)
  asm volatile("s_waitcnt vmcnt(8)" ::: "memory");
  __builtin_amdgcn_s_barrier();
  DS_NEXT(0, 0);

  for (int tp = 0; tp < 30; ++tp) {
    const int t = tp * 2;
    TILE(t,     0, 1, true, true, "vmcnt(6)", true);
    TILE(t + 1, 1, 0, true, true, "vmcnt(6)", true);
  }
  TILE(60, 0, 1, true,  true,  "vmcnt(6)", true);
  TILE(61, 1, 0, false, false, "vmcnt(4)", true);
  TILE(62, 0, 1, false, false, "vmcnt(0)", true);
  TILE(63, 1, 0, false, false, "vmcnt(0)", false);

#undef TILE
#undef MFMA_P1
#undef MFMA_P0
#undef DS_NEXT
#undef DS_AFH
#undef ISSUE_B
#undef ISSUE_A

  // epilogue: C/D layout col=lane&15, row=(lane>>4)*4+j
  const int er = (lane >> 4) * 4;
#pragma unroll
  for (int mt = 0; mt < 8; ++mt) {
#pragma unroll
    for (int j = 0; j < 4; ++j) {
      int r = wr * 128 + mt * 16 + er + j;
      if (r < rows) {
        float* op = out + (size_t)(row0 + r) * NDIM + col0 + wc * 64 + (lane & 15);
#pragma unroll
        for (int nt = 0; nt < 4; ++nt) op[nt * 16] = acc[mt][nt][j];
      }
    }
  }
}

// ---------------- fallback: direct fp32, reg-staged ----------------
__global__ __launch_bounds__(256) void moe_gemm_f32(
    const float* __restrict__ x, const float* __restrict__ w,
    const int* __restrict__ ms, float* __restrict__ out) {
  __shared__ __align__(16) char As[128 * 64 * 2];
  __shared__ __align__(16) char Bs[128 * 64 * 2];
  int sizes[NEXP];
#pragma unroll
  for (int i = 0; i < NEXP; ++i) sizes[i] = ms[i];
  const int bt = blockIdx.y;
  int e = 0, row0 = 0, rows = 0, acc_t = 0, start = 0;
  bool found = false;
#pragma unroll
  for (int i = 0; i < NEXP; ++i) {
    int nt = (sizes[i] + 127) >> 7;
    if (!found && bt < acc_t + nt) {
      found = true; e = i;
      int tt = bt - acc_t;
      row0 = start + tt * 128;
      rows = minI(sizes[i] - tt * 128, 128);
    }
    acc_t += nt; start += sizes[i];
  }
  if (!found) return;
  const int tid = threadIdx.x;
  const int lane = tid & 63;
  const int wave = tid >> 6;
  const int wm = wave >> 1, wn = wave & 1;
  const int col0 = blockIdx.x * 128;
  const float* wbase = w + (size_t)e * (size_t)NDIM * KDIM;
  const int sr = tid >> 1;
  const int sh = tid & 1;
  const float* aptr = x + (size_t)(row0 + sr) * KDIM + sh * 32;
  const float* bptr = wbase + (size_t)(col0 + sr) * KDIM + sh * 32;
  const bool aval = (sr < rows);
  f32x4 acc[4][4];
  const f32x4 zero = {0.f, 0.f, 0.f, 0.f};
#pragma unroll
  for (int i = 0; i < 4; ++i)
#pragma unroll
    for (int j = 0; j < 4; ++j) acc[i][j] = zero;
  for (int kb = 0; kb < KDIM / 64; ++kb) {
    {
      float4 v[8];
      if (aval) {
        const float4* p = (const float4*)(aptr + kb * 64);
#pragma unroll
        for (int j = 0; j < 8; ++j) v[j] = p[j];
      } else {
#pragma unroll
        for (int j = 0; j < 8; ++j) v[j] = make_float4(0.f, 0.f, 0.f, 0.f);
      }
#pragma unroll
      for (int j = 0; j < 4; ++j) {
        bf16x8 c = cvt8(v[2 * j], v[2 * j + 1]);
        int chunk = (sh * 4 + j) ^ (sr & 7);
        *(bf16x8*)(As + sr * 128 + chunk * 16) = c;
      }
    }
    {
      const float4* p = (const float4*)(bptr + kb * 64);
      float4 u[8];
#pragma unroll
      for (int j = 0; j < 8; ++j) u[j] = p[j];
#pragma unroll
      for (int j = 0; j < 4; ++j) {
        bf16x8 c = cvt8(u[2 * j], u[2 * j + 1]);
        int chunk = (sh * 4 + j) ^ (sr & 7);
        *(bf16x8*)(Bs + sr * 128 + chunk * 16) = c;
      }
    }
    __syncthreads();
#pragma unroll
    for (int ks = 0; ks < 2; ++ks) {
      bf16x8 afr[4], bfv[4];
#pragma unroll
      for (int mt = 0; mt < 4; ++mt) {
        int r = wm * 64 + mt * 16 + (lane & 15);
        int chunk = (ks * 4 + (lane >> 4)) ^ (r & 7);
        afr[mt] = *(const bf16x8*)(As + r * 128 + chunk * 16);
      }
#pragma unroll
      for (int nt = 0; nt < 4; ++nt) {
        int r = wn * 64 + nt * 16 + (lane & 15);
        int chunk = (ks * 4 + (lane >> 4)) ^ (r & 7);
        bfv[nt] = *(const bf16x8*)(Bs + r * 128 + chunk * 16);
      }
#pragma unroll
      for (int mt = 0; mt < 4; ++mt)
#pragma unroll
        for (int nt = 0; nt < 4; ++nt)
          acc[mt][nt] = __builtin_amdgcn_mfma_f32_16x16x32_bf16(
              afr[mt], bfv[nt], acc[mt][nt], 0, 0, 0);
    }
    __syncthreads();
  }
#pragma unroll
  for (int mt = 0; mt < 4; ++mt) {
#pragma unroll
    for (int j = 0; j < 4; ++j) {
      int r = wm * 64 + mt * 16 + (lane >> 4) * 4 + j;
      if (r < rows) {
        float* op = out + (size_t)(row0 + r) * NDIM + col0 + wn * 64 + (lane & 15);
#pragma unroll
        for (int nt = 0; nt < 4; ++nt) op[nt * 16] = acc[mt][nt][j];
      }
    }
  }
}

extern "C" void kernel_launch(void* const* d_in, const int* in_sizes, int n_in,
                              void* d_out, int out_size, void* d_ws, size_t ws_size,
                              hipStream_t stream) {
  const float* x = (const float*)d_in[0];
  const float* w = (const float*)d_in[1];
  const int* ms = (const int*)d_in[2];
  float* out = (float*)d_out;
  const size_t nx = (size_t)M_TOTAL * KDIM;
  const size_t nw = (size_t)NEXP * NDIM * KDIM;
  const size_t need = (nx + nw) * sizeof(__hip_bfloat16);
  if (ws_size >= need) {
    __hip_bfloat16* xb = (__hip_bfloat16*)d_ws;
    __hip_bfloat16* wb = xb + nx;
    cvt_both<<<2048, 256, 0, stream>>>(x, w, (bf16x8*)xb, (bf16x8*)wb);
    moe_gemm_pipe<<<dim3(NWG), dim3(512), 0, stream>>>(xb, wb, ms, out);
  } else {
    moe_gemm_f32<<<dim3(16, 135), dim3(256), 0, stream>>>(x, w, ms, out);
  }
}